// Round 10
// baseline (283.428 us; speedup 1.0000x reference)
//
#include <hip/hip_runtime.h>

#define NPTS 32768
#define CH 64
#define KNN 16
#define NE (NPTS*KNN)
#define EPS 1e-5f
#define NREP 32

// raw stats groups: NREP replicas x 128 floats; sums at [c], sumsq at [64+c]
#define G_P   0
#define G_BN1 (1*NREP*128)
#define G_W1  (2*NREP*128)
#define G_W2  (3*NREP*128)
#define G_BN2 (4*NREP*128)
#define G_BN3 (5*NREP*128)
#define STATS_FLOATS (6*NREP*128)

// finalized scale/shift for W1 only: [sc 0..63][sh 64..127]
#define F_W1  (STATS_FLOATS)

#define OFF_T1  (STATS_FLOATS + 1024)
#define SZ_NC   (NPTS*CH)
// bf16 buffers (NPTS*32 uints each)
#define OFF_K   (OFF_T1 + SZ_NC)
#define OFF_Q   (OFF_K + NPTS*32)
#define OFF_V   (OFF_Q + NPTS*32)
#define OFF_A2  (OFF_V + NPTS*32)      /* NE*4 uints (8 bf16/edge) */
#define OFF_OUT (OFF_A2 + NE*4)
#define OFF_U   (OFF_OUT + SZ_NC)      /* NE*4 floats; aliased with H3 */
#define OFF_H3  OFF_U

typedef unsigned int uint;

__device__ __forceinline__ float frelu(float x){ return fmaxf(x, 0.f); }
__device__ __forceinline__ float bflo(uint u){ return __uint_as_float(u<<16); }
__device__ __forceinline__ float bfhi(uint u){ return __uint_as_float(u & 0xffff0000u); }
__device__ __forceinline__ uint bfpack(float lo, float hi){
    uint a = __float_as_uint(lo), b = __float_as_uint(hi);
    a = (a + 0x7fffu + ((a>>16)&1u)) >> 16;
    b = ((b + 0x7fffu + ((b>>16)&1u)) >> 16) << 16;
    return a | b;
}

// ---------- finalize one stats group -> [sc|sh] (kept only for W1) ----------
__global__ __launch_bounds__(128) void k_fin1(
    const float* __restrict__ g, float inv, const float* __restrict__ gm,
    const float* __restrict__ bt, float* __restrict__ o, int nch)
{
    __shared__ float s_tmp[128];
    const int tid = threadIdx.x;
    float t = 0.f;
    #pragma unroll
    for (int r=0;r<NREP;++r) t += g[r*128+tid];
    s_tmp[tid] = t;
    __syncthreads();
    if (tid < 64) {
        if (tid < nch) {
            float m = s_tmp[tid]*inv;
            float v = s_tmp[64+tid]*inv - m*m;
            float s = gm[tid]*rsqrtf(v+EPS);
            o[tid] = s; o[64+tid] = bt[tid] - m*s;
        } else { o[tid]=0.f; o[64+tid]=0.f; }
    }
}

// ---------- merged: blocks 0..2047 = u precompute + p-bn stats; 2048..2303 = gemm1 ----------
__global__ __launch_bounds__(256) void k_pg(
    const float* __restrict__ pos, const int* __restrict__ esrc,
    const float* __restrict__ p1w, const float* __restrict__ p1b,
    float4* __restrict__ u4, float* __restrict__ gstatP,
    const float* __restrict__ in, const float* __restrict__ W,
    float* __restrict__ out, float* __restrict__ gstatB)
{
    __shared__ float Wt[CH*16];
    __shared__ float red[4][32];
    const int tid = threadIdx.x;
    const int wv = tid >> 6;
    if (blockIdx.x < 2048) {
        // ---- pstats_u ----
        const float w0=p1w[0],w1=p1w[1],w2=p1w[2],w3=p1w[3],w4=p1w[4],w5=p1w[5],w6=p1w[6],w7=p1w[7],w8=p1w[8];
        const float b0=p1b[0],b1=p1b[1],b2=p1b[2];
        const int e = blockIdx.x*256 + tid;
        const int sj = esrc[e]; const int d = e >> 4;
        float ax = pos[3*sj]-pos[3*d], ay = pos[3*sj+1]-pos[3*d+1], az = pos[3*sj+2]-pos[3*d+2];
        float u0 = w0*ax+w1*ay+w2*az+b0;
        float u1 = w3*ax+w4*ay+w5*az+b1;
        float u2 = w6*ax+w7*ay+w8*az+b2;
        u4[e] = make_float4(u0,u1,u2,0.f);
        float s0=u0,s1=u1,s2=u2,q0=u0*u0,q1=u1*u1,q2=u2*u2;
        #pragma unroll
        for (int m=32;m>=1;m>>=1){
            s0+=__shfl_xor(s0,m); s1+=__shfl_xor(s1,m); s2+=__shfl_xor(s2,m);
            q0+=__shfl_xor(q0,m); q1+=__shfl_xor(q1,m); q2+=__shfl_xor(q2,m);
        }
        if ((tid&63)==0){ red[wv][0]=s0; red[wv][1]=s1; red[wv][2]=s2;
                          red[wv][3]=q0; red[wv][4]=q1; red[wv][5]=q2; }
        __syncthreads();
        float* g = gstatP + (blockIdx.x & (NREP-1))*128;
        if (tid < 3)      atomicAdd(&g[tid],        red[0][tid]+red[1][tid]+red[2][tid]+red[3][tid]);
        else if (tid < 6) atomicAdd(&g[64+(tid-3)], red[0][tid]+red[1][tid]+red[2][tid]+red[3][tid]);
        return;
    }
    // ---- gemm1 (no input BN) ----
    const int bid = blockIdx.x - 2048;
    const int rb = bid >> 2;
    const int c0 = (bid & 3)*16;
    #pragma unroll
    for (int ch=0; ch<4; ++ch){
        const int idx = ch*256 + tid;
        Wt[idx] = W[(size_t)(c0 + (idx & 15))*CH + (idx >> 4)];
    }
    __syncthreads();
    const int row0 = rb*512 + tid;
    const float4* iv0 = (const float4*)(in + (size_t)row0*CH);
    const float4* iv1 = (const float4*)(in + (size_t)(row0+256)*CH);
    const float4* Wt4 = (const float4*)Wt;
    float4 A0=make_float4(0,0,0,0),A1=A0,A2=A0,A3=A0;
    float4 B0=A0,B1=A0,B2=A0,B3=A0;
    #pragma unroll 1
    for (int jj=0;jj<16;++jj){
        float4 x0 = iv0[jj], x1 = iv1[jj];
        const float4* wb = &Wt4[jj*16];
        #define MSTEP(xa, xb, base) { \
            float4 w_0=wb[(base)+0], w_1=wb[(base)+1], w_2=wb[(base)+2], w_3=wb[(base)+3]; \
            A0.x+=(xa)*w_0.x; A0.y+=(xa)*w_0.y; A0.z+=(xa)*w_0.z; A0.w+=(xa)*w_0.w; \
            A1.x+=(xa)*w_1.x; A1.y+=(xa)*w_1.y; A1.z+=(xa)*w_1.z; A1.w+=(xa)*w_1.w; \
            A2.x+=(xa)*w_2.x; A2.y+=(xa)*w_2.y; A2.z+=(xa)*w_2.z; A2.w+=(xa)*w_2.w; \
            A3.x+=(xa)*w_3.x; A3.y+=(xa)*w_3.y; A3.z+=(xa)*w_3.z; A3.w+=(xa)*w_3.w; \
            B0.x+=(xb)*w_0.x; B0.y+=(xb)*w_0.y; B0.z+=(xb)*w_0.z; B0.w+=(xb)*w_0.w; \
            B1.x+=(xb)*w_1.x; B1.y+=(xb)*w_1.y; B1.z+=(xb)*w_1.z; B1.w+=(xb)*w_1.w; \
            B2.x+=(xb)*w_2.x; B2.y+=(xb)*w_2.y; B2.z+=(xb)*w_2.z; B2.w+=(xb)*w_2.w; \
            B3.x+=(xb)*w_3.x; B3.y+=(xb)*w_3.y; B3.z+=(xb)*w_3.z; B3.w+=(xb)*w_3.w; }
        MSTEP(x0.x, x1.x, 0) MSTEP(x0.y, x1.y, 4) MSTEP(x0.z, x1.z, 8) MSTEP(x0.w, x1.w, 12)
        #undef MSTEP
    }
    float4* ov0 = (float4*)(out + (size_t)row0*CH + c0);
    float4* ov1 = (float4*)(out + (size_t)(row0+256)*CH + c0);
    ov0[0]=A0; ov0[1]=A1; ov0[2]=A2; ov0[3]=A3;
    ov1[0]=B0; ov1[1]=B1; ov1[2]=B2; ov1[3]=B3;
    #define STATQ(q, A, B) { \
        float4 s = make_float4(A.x+B.x, A.y+B.y, A.z+B.z, A.w+B.w); \
        float4 sq = make_float4(A.x*A.x+B.x*B.x, A.y*A.y+B.y*B.y, A.z*A.z+B.z*B.z, A.w*A.w+B.w*B.w); \
        _Pragma("unroll") \
        for (int m=32;m>=1;m>>=1){ \
            s.x+=__shfl_xor(s.x,m); s.y+=__shfl_xor(s.y,m); \
            s.z+=__shfl_xor(s.z,m); s.w+=__shfl_xor(s.w,m); \
            sq.x+=__shfl_xor(sq.x,m); sq.y+=__shfl_xor(sq.y,m); \
            sq.z+=__shfl_xor(sq.z,m); sq.w+=__shfl_xor(sq.w,m); } \
        if ((tid&63)==0){ \
            red[wv][q*4+0]=s.x; red[wv][q*4+1]=s.y; red[wv][q*4+2]=s.z; red[wv][q*4+3]=s.w; \
            red[wv][16+q*4+0]=sq.x; red[wv][16+q*4+1]=sq.y; red[wv][16+q*4+2]=sq.z; red[wv][16+q*4+3]=sq.w; } }
    STATQ(0, A0, B0) STATQ(1, A1, B1) STATQ(2, A2, B2) STATQ(3, A3, B3)
    #undef STATQ
    __syncthreads();
    if (tid < 32) {
        float t = red[0][tid]+red[1][tid]+red[2][tid]+red[3][tid];
        int dstc = (tid<16) ? (c0+tid) : (64 + c0 + (tid-16));
        atomicAdd(&gstatB[(bid & (NREP-1))*128 + dstc], t);
    }
}

// ---------- k/q/v: grid 768; inline BN1 finalize; bf16-packed outputs ----------
__global__ __launch_bounds__(256) void k_kqv(
    const float* __restrict__ t1,
    const float* __restrict__ Wk, const float* __restrict__ bk,
    const float* __restrict__ Wq, const float* __restrict__ bq,
    const float* __restrict__ Wv, const float* __restrict__ bv,
    const float* __restrict__ bnrep, const float* __restrict__ bn1g,
    const float* __restrict__ bn1b,
    uint* __restrict__ kout, uint* __restrict__ qout, uint* __restrict__ vout)
{
    __shared__ float Wt[CH*16];
    __shared__ float fbnL[128];
    __shared__ float4 bias4[4];
    const int tid = threadIdx.x;
    const int m = blockIdx.x / 256;
    const int rem = blockIdx.x & 255;
    const int rb = rem >> 2;
    const int c0 = (rem & 3)*16;
    const float* W  = (m==0) ? Wk : (m==1 ? Wq : Wv);
    const float* bs = (m==0) ? bk : (m==1 ? bq : bv);
    uint* o         = (m==0) ? kout : (m==1 ? qout : vout);
    #pragma unroll
    for (int ch=0; ch<4; ++ch){
        const int idx = ch*256 + tid;
        Wt[idx] = W[(size_t)(c0 + (idx & 15))*CH + (idx >> 4)];
    }
    if (tid < 128){
        float t = 0.f;
        #pragma unroll
        for (int r=0;r<NREP;++r) t += bnrep[r*128+tid];
        fbnL[tid] = t;
    }
    if (tid < 4)  bias4[tid] = ((const float4*)(bs + c0))[tid];
    __syncthreads();
    if (tid < 64){
        float mm = fbnL[tid]*(1.f/NPTS);
        float vv = fbnL[64+tid]*(1.f/NPTS) - mm*mm;
        float ss = bn1g[tid]*rsqrtf(vv+EPS);
        fbnL[tid] = ss; fbnL[64+tid] = bn1b[tid] - mm*ss;
    }
    __syncthreads();
    const float4* fL = (const float4*)fbnL;

    const int row0 = rb*512 + tid;
    const float4* iv0 = (const float4*)(t1 + (size_t)row0*CH);
    const float4* iv1 = (const float4*)(t1 + (size_t)(row0+256)*CH);
    const float4* Wt4 = (const float4*)Wt;
    float4 A0=bias4[0],A1=bias4[1],A2=bias4[2],A3=bias4[3];
    float4 B0=bias4[0],B1=bias4[1],B2=bias4[2],B3=bias4[3];
    #pragma unroll 1
    for (int jj=0;jj<16;++jj){
        float4 x0 = iv0[jj], x1 = iv1[jj];
        float4 s4 = fL[jj], h4 = fL[16+jj];
        x0.x=frelu(x0.x*s4.x+h4.x); x0.y=frelu(x0.y*s4.y+h4.y);
        x0.z=frelu(x0.z*s4.z+h4.z); x0.w=frelu(x0.w*s4.w+h4.w);
        x1.x=frelu(x1.x*s4.x+h4.x); x1.y=frelu(x1.y*s4.y+h4.y);
        x1.z=frelu(x1.z*s4.z+h4.z); x1.w=frelu(x1.w*s4.w+h4.w);
        const float4* wb = &Wt4[jj*16];
        #define MSTEP(xa, xb, base) { \
            float4 w_0=wb[(base)+0], w_1=wb[(base)+1], w_2=wb[(base)+2], w_3=wb[(base)+3]; \
            A0.x+=(xa)*w_0.x; A0.y+=(xa)*w_0.y; A0.z+=(xa)*w_0.z; A0.w+=(xa)*w_0.w; \
            A1.x+=(xa)*w_1.x; A1.y+=(xa)*w_1.y; A1.z+=(xa)*w_1.z; A1.w+=(xa)*w_1.w; \
            A2.x+=(xa)*w_2.x; A2.y+=(xa)*w_2.y; A2.z+=(xa)*w_2.z; A2.w+=(xa)*w_2.w; \
            A3.x+=(xa)*w_3.x; A3.y+=(xa)*w_3.y; A3.z+=(xa)*w_3.z; A3.w+=(xa)*w_3.w; \
            B0.x+=(xb)*w_0.x; B0.y+=(xb)*w_0.y; B0.z+=(xb)*w_0.z; B0.w+=(xb)*w_0.w; \
            B1.x+=(xb)*w_1.x; B1.y+=(xb)*w_1.y; B1.z+=(xb)*w_1.z; B1.w+=(xb)*w_1.w; \
            B2.x+=(xb)*w_2.x; B2.y+=(xb)*w_2.y; B2.z+=(xb)*w_2.z; B2.w+=(xb)*w_2.w; \
            B3.x+=(xb)*w_3.x; B3.y+=(xb)*w_3.y; B3.z+=(xb)*w_3.z; B3.w+=(xb)*w_3.w; }
        MSTEP(x0.x, x1.x, 0) MSTEP(x0.y, x1.y, 4) MSTEP(x0.z, x1.z, 8) MSTEP(x0.w, x1.w, 12)
        #undef MSTEP
    }
    uint4 pa, pb_;
    pa.x = bfpack(A0.x,A0.y); pa.y = bfpack(A0.z,A0.w);
    pa.z = bfpack(A1.x,A1.y); pa.w = bfpack(A1.z,A1.w);
    pb_.x = bfpack(A2.x,A2.y); pb_.y = bfpack(A2.z,A2.w);
    pb_.z = bfpack(A3.x,A3.y); pb_.w = bfpack(A3.z,A3.w);
    uint4* o0 = (uint4*)(o + (size_t)row0*32 + (c0>>1));
    o0[0]=pa; o0[1]=pb_;
    pa.x = bfpack(B0.x,B0.y); pa.y = bfpack(B0.z,B0.w);
    pa.z = bfpack(B1.x,B1.y); pa.w = bfpack(B1.z,B1.w);
    pb_.x = bfpack(B2.x,B2.y); pb_.y = bfpack(B2.z,B2.w);
    pb_.z = bfpack(B3.x,B3.y); pb_.w = bfpack(B3.z,B3.w);
    uint4* o1 = (uint4*)(o + (size_t)(row0+256)*32 + (c0>>1));
    o1[0]=pa; o1[1]=pb_;
}

// ---------- w_bn1 stats; inline P finalize (lane = channel, bf16 k/q) ----------
__global__ __launch_bounds__(256) void k_edge1(
    const int* __restrict__ esrc, const float4* __restrict__ u4,
    const unsigned short* __restrict__ kbuf, const unsigned short* __restrict__ qbuf,
    const float* __restrict__ gP, const float* __restrict__ pg,
    const float* __restrict__ pb,
    const float* __restrict__ p2w, const float* __restrict__ p2b,
    float* __restrict__ gstat)
{
    __shared__ float red[4][128];
    __shared__ float pf[6];
    const int tid = threadIdx.x;
    const int c = tid & 63, wv = tid >> 6;
    if (tid < 6){
        int idx = (tid<3) ? tid : 64+(tid-3);
        float t = 0.f;
        #pragma unroll
        for (int r=0;r<NREP;++r) t += gP[r*128+idx];
        pf[tid] = t;
    }
    __syncthreads();
    const float m0=pf[0]*(1.f/NE), m1=pf[1]*(1.f/NE), m2=pf[2]*(1.f/NE);
    const float scp0=pg[0]*rsqrtf(pf[3]*(1.f/NE)-m0*m0+EPS);
    const float scp1=pg[1]*rsqrtf(pf[4]*(1.f/NE)-m1*m1+EPS);
    const float scp2=pg[2]*rsqrtf(pf[5]*(1.f/NE)-m2*m2+EPS);
    const float shp0=pb[0]-m0*scp0, shp1=pb[1]-m1*scp1, shp2=pb[2]-m2*scp2;
    const float w0 = p2w[c*3+0], w1 = p2w[c*3+1], w2 = p2w[c*3+2], bc = p2b[c];

    const int gw = blockIdx.x*4 + wv;      // 32768 waves
    const int chunk = NE/32768;            // 16 edges/wave
    const int e0 = gw*chunk;
    float s=0.f, q=0.f;
    #pragma unroll 4
    for (int e = e0; e < e0+chunk; ++e) {
        int sj = esrc[e]; int d = e >> 4;
        float4 uu = u4[e];
        float r0 = frelu(uu.x*scp0+shp0);
        float r1 = frelu(uu.y*scp1+shp1);
        float r2 = frelu(uu.z*scp2+shp2);
        float kv = __uint_as_float(((uint)kbuf[(size_t)sj*CH+c])<<16);
        float qv = __uint_as_float(((uint)qbuf[(size_t)d*CH+c])<<16);
        float a = kv - qv + (r0*w0 + r1*w1 + r2*w2 + bc);
        s += a; q += a*a;
    }
    red[wv][c] = s; red[wv][64+c] = q;
    __syncthreads();
    if (tid < 128) {
        float t = red[0][tid]+red[1][tid]+red[2][tid]+red[3][tid];
        atomicAdd(&gstat[(blockIdx.x & (NREP-1))*128 + tid], t);
    }
}

// ---------- a2 = relu(bn_w1(apre))@w1^T+b1 ; inline P; thread = edge; bf16 ----------
__global__ __launch_bounds__(256) void k_edge2(
    const int* __restrict__ esrc, const float4* __restrict__ u4,
    const uint* __restrict__ kbuf, const uint* __restrict__ qbuf,
    const float* __restrict__ gP, const float* __restrict__ pg,
    const float* __restrict__ pb,
    const float* __restrict__ p2w, const float* __restrict__ p2b,
    const float* __restrict__ fW1,
    const float* __restrict__ w1w, const float* __restrict__ w1bias,
    uint* __restrict__ a2out, float* __restrict__ gstat)
{
    __shared__ float red[4][16];
    __shared__ float pf[6];
    const int tid = threadIdx.x;
    if (tid < 6){
        int idx = (tid<3) ? tid : 64+(tid-3);
        float t = 0.f;
        #pragma unroll
        for (int r=0;r<NREP;++r) t += gP[r*128+idx];
        pf[tid] = t;
    }
    __syncthreads();
    const float m0=pf[0]*(1.f/NE), m1=pf[1]*(1.f/NE), m2=pf[2]*(1.f/NE);
    const float scp0=pg[0]*rsqrtf(pf[3]*(1.f/NE)-m0*m0+EPS);
    const float scp1=pg[1]*rsqrtf(pf[4]*(1.f/NE)-m1*m1+EPS);
    const float scp2=pg[2]*rsqrtf(pf[5]*(1.f/NE)-m2*m2+EPS);
    const float shp0=pb[0]-m0*scp0, shp1=pb[1]-m1*scp1, shp2=pb[2]-m2*scp2;

    const int e = blockIdx.x*256 + tid;    // 2048 blocks, one edge/thread
    const int sj = esrc[e]; const int d = e >> 4;
    float4 uu = u4[e];
    const float r0 = frelu(uu.x*scp0+shp0);
    const float r1 = frelu(uu.y*scp1+shp1);
    const float r2 = frelu(uu.z*scp2+shp2);
    const uint4* kv = (const uint4*)(kbuf + (size_t)sj*32);
    const uint4* qv = (const uint4*)(qbuf + (size_t)d*32);
    float a2a[8];
    #pragma unroll
    for (int j=0;j<8;++j) a2a[j] = w1bias[j];
    #pragma unroll
    for (int cc=0; cc<8; ++cc) {
        uint4 ku = kv[cc], qu = qv[cc];
        const int c0 = cc*8;
        float kq[8];
        kq[0]=bflo(ku.x)-bflo(qu.x); kq[1]=bfhi(ku.x)-bfhi(qu.x);
        kq[2]=bflo(ku.y)-bflo(qu.y); kq[3]=bfhi(ku.y)-bfhi(qu.y);
        kq[4]=bflo(ku.z)-bflo(qu.z); kq[5]=bfhi(ku.z)-bfhi(qu.z);
        kq[6]=bflo(ku.w)-bflo(qu.w); kq[7]=bfhi(ku.w)-bfhi(qu.w);
        #pragma unroll
        for (int p=0;p<8;++p){
            const int c = c0+p;
            float b = frelu((kq[p] + r0*p2w[c*3]+r1*p2w[c*3+1]+r2*p2w[c*3+2]+p2b[c])*fW1[c]+fW1[64+c]);
            #pragma unroll
            for (int j=0;j<8;++j) a2a[j] += b*w1w[j*64+c];
        }
    }
    uint4 au;
    au.x = bfpack(a2a[0],a2a[1]); au.y = bfpack(a2a[2],a2a[3]);
    au.z = bfpack(a2a[4],a2a[5]); au.w = bfpack(a2a[6],a2a[7]);
    ((uint4*)a2out)[e] = au;
    float q8[8];
    #pragma unroll
    for (int j=0;j<8;++j) q8[j]=a2a[j]*a2a[j];
    #pragma unroll
    for (int m=32;m>=1;m>>=1){
        #pragma unroll
        for (int j=0;j<8;++j){ a2a[j]+=__shfl_xor(a2a[j],m); q8[j]+=__shfl_xor(q8[j],m); }
    }
    const int wv = tid>>6;
    if ((tid&63)==0){
        #pragma unroll
        for (int j=0;j<8;++j){ red[wv][j]=a2a[j]; red[wv][8+j]=q8[j]; }
    }
    __syncthreads();
    if (tid < 16) {
        float t = red[0][tid]+red[1][tid]+red[2][tid]+red[3][tid];
        int dstc = (tid<8) ? tid : (64 + tid - 8);
        atomicAdd(&gstat[(blockIdx.x & (NREP-1))*128 + dstc], t);
    }
}

// ---------- inline P+W2 finalize; bn_w2 + w2 + softmax (A); aggregation (B) + bn2 stats ----------
__global__ __launch_bounds__(256) void k_attn(
    const int* __restrict__ esrc, const float4* __restrict__ u4,
    const uint* __restrict__ vbuf, const uint* __restrict__ a2buf,
    const float* __restrict__ gP, const float* __restrict__ pg,
    const float* __restrict__ pb,
    const float* __restrict__ p2w, const float* __restrict__ p2b,
    const float* __restrict__ gW2, const float* __restrict__ w2g,
    const float* __restrict__ w2bb,
    const float* __restrict__ w2w, const float* __restrict__ w2bias,
    float* __restrict__ outbuf, float* __restrict__ gstat)
{
    __shared__ float red[4][128];
    __shared__ float att[256][8];
    __shared__ float rrL[256][4];
    __shared__ int   sjL[256];
    __shared__ float cf[22];     // [0..5] P raw; [6..13] W2 sum; [14..21] W2 sumsq
    const int tid = threadIdx.x;
    if (tid < 6){
        int idx = (tid<3) ? tid : 64+(tid-3);
        float t = 0.f;
        #pragma unroll
        for (int r=0;r<NREP;++r) t += gP[r*128+idx];
        cf[tid] = t;
    } else if (tid < 22){
        int j = tid - 6;
        int idx = (j<8) ? j : 64+(j-8);
        float t = 0.f;
        #pragma unroll
        for (int r=0;r<NREP;++r) t += gW2[r*128+idx];
        cf[tid] = t;
    }
    __syncthreads();
    const float m0=cf[0]*(1.f/NE), m1=cf[1]*(1.f/NE), m2=cf[2]*(1.f/NE);
    const float scp0=pg[0]*rsqrtf(cf[3]*(1.f/NE)-m0*m0+EPS);
    const float scp1=pg[1]*rsqrtf(cf[4]*(1.f/NE)-m1*m1+EPS);
    const float scp2=pg[2]*rsqrtf(cf[5]*(1.f/NE)-m2*m2+EPS);
    const float shp0=pb[0]-m0*scp0, shp1=pb[1]-m1*scp1, shp2=pb[2]-m2*scp2;

    const int t = tid & 15;
    const int i = blockIdx.x*16 + (tid>>4);
    const int e = i*KNN + t;
    const int sj = esrc[e];
    sjL[tid] = sj;
    {
        float4 uu = u4[e];
        rrL[tid][0] = frelu(uu.x*scp0+shp0);
        rrL[tid][1] = frelu(uu.y*scp1+shp1);
        rrL[tid][2] = frelu(uu.z*scp2+shp2);
    }
    // ---- phase A ----
    {
        float sc2[8], sh2[8];
        #pragma unroll
        for (int j2=0;j2<8;++j2){
            float mm = cf[6+j2]*(1.f/NE);
            float vv = cf[14+j2]*(1.f/NE) - mm*mm;
            float ss = w2g[j2]*rsqrtf(vv+EPS);
            sc2[j2]=ss; sh2[j2]=w2bb[j2]-mm*ss;
        }
        uint4 au = ((const uint4*)a2buf)[e];
        float bb[8];
        bb[0]=frelu(bflo(au.x)*sc2[0]+sh2[0]); bb[1]=frelu(bfhi(au.x)*sc2[1]+sh2[1]);
        bb[2]=frelu(bflo(au.y)*sc2[2]+sh2[2]); bb[3]=frelu(bfhi(au.y)*sc2[3]+sh2[3]);
        bb[4]=frelu(bflo(au.z)*sc2[4]+sh2[4]); bb[5]=frelu(bfhi(au.z)*sc2[5]+sh2[5]);
        bb[6]=frelu(bflo(au.w)*sc2[6]+sh2[6]); bb[7]=frelu(bfhi(au.w)*sc2[7]+sh2[7]);
        float at[8];
        #pragma unroll
        for (int s=0;s<8;++s){
            float a3 = w2bias[s];
            #pragma unroll
            for (int u=0;u<8;++u) a3 += bb[u]*w2w[s*8+u];
            float m = a3;
            #pragma unroll
            for (int msk=8;msk>=1;msk>>=1) m = fmaxf(m, __shfl_xor(m,msk));
            float p = __expf(a3-m);
            float ssm = p;
            #pragma unroll
            for (int msk=8;msk>=1;msk>>=1) ssm += __shfl_xor(ssm,msk);
            at[s] = p/ssm;
        }
        ((float4*)att[tid])[0] = make_float4(at[0],at[1],at[2],at[3]);
        ((float4*)att[tid])[1] = make_float4(at[4],at[5],at[6],at[7]);
    }
    __syncthreads();
    // ---- phase B: thread owns channels 4t..4t+3 of point i ----
    const int base = (tid>>4)*16;
    const int c0 = 4*t;
    const int ho = (t&1);
    float pw[12], pbv[4];
    #pragma unroll
    for (int k2=0;k2<12;++k2) pw[k2] = p2w[c0*3+k2];
    #pragma unroll
    for (int k2=0;k2<4;++k2)  pbv[k2] = p2b[c0+k2];
    float4 res = make_float4(0,0,0,0);
    #pragma unroll 4
    for (int n=0; n<16; ++n){
        const int sjn = sjL[base+n];
        uint2 vv = ((const uint2*)(vbuf + (size_t)sjn*32))[t];
        const float v0=bflo(vv.x), v1=bfhi(vv.x), v2=bflo(vv.y), v3=bfhi(vv.y);
        const float rr0 = rrL[base+n][0], rr1 = rrL[base+n][1], rr2 = rrL[base+n][2];
        float4 a4 = ((const float4*)att[base+n])[ho];
        res.x += a4.x*(v0 + rr0*pw[0]+rr1*pw[1]+rr2*pw[2]+pbv[0]);
        res.y += a4.y*(v1 + rr0*pw[3]+rr1*pw[4]+rr2*pw[5]+pbv[1]);
        res.z += a4.z*(v2 + rr0*pw[6]+rr1*pw[7]+rr2*pw[8]+pbv[2]);
        res.w += a4.w*(v3 + rr0*pw[9]+rr1*pw[10]+rr2*pw[11]+pbv[3]);
    }
    ((float4*)outbuf)[(size_t)i*16 + t] = res;

    // fused bn2 stats
    float4 sq = make_float4(res.x*res.x, res.y*res.y, res.z*res.z, res.w*res.w);
    #pragma unroll
    for (int msk=32;msk>=16;msk>>=1){
        res.x+=__shfl_xor(res.x,msk); res.y+=__shfl_xor(res.y,msk);
        res.z+=__shfl_xor(res.z,msk); res.w+=__shfl_xor(res.w,msk);
        sq.x+=__shfl_xor(sq.x,msk);  sq.y+=__shfl_xor(sq.y,msk);
        sq.z+=__shfl_xor(sq.z,msk);  sq.w+=__shfl_xor(sq.w,msk);
    }
    const int wv = tid>>6;
    if ((tid&63) < 16){
        red[wv][t*4+0]=res.x; red[wv][t*4+1]=res.y; red[wv][t*4+2]=res.z; red[wv][t*4+3]=res.w;
        red[wv][64+t*4+0]=sq.x; red[wv][64+t*4+1]=sq.y; red[wv][64+t*4+2]=sq.z; red[wv][64+t*4+3]=sq.w;
    }
    __syncthreads();
    if (tid < 128) {
        float tt = red[0][tid]+red[1][tid]+red[2][tid]+red[3][tid];
        atomicAdd(&gstat[(blockIdx.x & (NREP-1))*128 + tid], tt);
    }
}

// ---------- gemm2: inline BN2 finalize, bn+relu input, W3 matvec, bn3 stats ----------
__global__ __launch_bounds__(256) void k_gemm_bn(
    const float* __restrict__ in, const float* __restrict__ W,
    float* __restrict__ out,
    const float* __restrict__ bnrep, const float* __restrict__ gma,
    const float* __restrict__ bta,
    float* __restrict__ gstat)
{
    __shared__ float Wt[CH*16];
    __shared__ float fbnL[128];
    __shared__ float red[4][32];
    const int tid = threadIdx.x;
    const int wv = tid >> 6;
    const int rb = blockIdx.x >> 2;
    const int c0 = (blockIdx.x & 3)*16;
    #pragma unroll
    for (int ch=0; ch<4; ++ch){
        const int idx = ch*256 + tid;
        Wt[idx] = W[(size_t)(c0 + (idx & 15))*CH + (idx >> 4)];
    }
    if (tid < 128){
        float t = 0.f;
        #pragma unroll
        for (int r=0;r<NREP;++r) t += bnrep[r*128+tid];
        fbnL[tid] = t;
    }
    __syncthreads();
    if (tid < 64){
        float mm = fbnL[tid]*(1.f/NPTS);
        float vv = fbnL[64+tid]*(1.f/NPTS) - mm*mm;
        float ss = gma[tid]*rsqrtf(vv+EPS);
        fbnL[tid] = ss; fbnL[64+tid] = bta[tid] - mm*ss;
    }
    __syncthreads();
    const float4* fL = (const float4*)fbnL;

    const int row0 = rb*512 + tid;
    const float4* iv0 = (const float4*)(in + (size_t)row0*CH);
    const float4* iv1 = (const float4*)(in + (size_t)(row0+256)*CH);
    const float4* Wt4 = (const float4*)Wt;
    float4 A0=make_float4(0,0,0,0),A1=A0,A2=A0,A3=A0;
    float4 B0=A0,B1=A0,B2=A0,B3=A0;
    #pragma unroll 1
    for (int jj=0;jj<16;++jj){
        float4 x0 = iv0[jj], x1 = iv1[jj];
        float4 s4 = fL[jj], h4 = fL[16+jj];
        x0.x=frelu(x0.x*s4.x+h4.x); x0.y=frelu(x0.y*s4.y+h4.y);
        x0.z=frelu(x0.z*s4.z+h4.z); x0.w=frelu(x0.w*s4.w+h4.w);
        x1.x=frelu(x1.x*s4.x+h4.x); x1.y=frelu(x1.y*s4.y+h4.y);
        x1.z=frelu(x1.z*s4.z+h4.z); x1.w=frelu(x1.w*s4.w+h4.w);
        const float4* wb = &Wt4[jj*16];
        #define MSTEP(xa, xb, base) { \
            float4 w_0=wb[(base)+0], w_1=wb[(base)+1], w_2=wb[(base)+2], w_3=wb[(base)+3]; \
            A0.x+=(xa)*w_0.x; A0.y+=(xa)*w_0.y; A0.z+=(xa)*w_0.z; A0.w+=(xa)*w_0.w; \
            A1.x+=(xa)*w_1.x; A1.y+=(xa)*w_1.y; A1.z+=(xa)*w_1.z; A1.w+=(xa)*w_1.w; \
            A2.x+=(xa)*w_2.x; A2.y+=(xa)*w_2.y; A2.z+=(xa)*w_2.z; A2.w+=(xa)*w_2.w; \
            A3.x+=(xa)*w_3.x; A3.y+=(xa)*w_3.y; A3.z+=(xa)*w_3.z; A3.w+=(xa)*w_3.w; \
            B0.x+=(xb)*w_0.x; B0.y+=(xb)*w_0.y; B0.z+=(xb)*w_0.z; B0.w+=(xb)*w_0.w; \
            B1.x+=(xb)*w_1.x; B1.y+=(xb)*w_1.y; B1.z+=(xb)*w_1.z; B1.w+=(xb)*w_1.w; \
            B2.x+=(xb)*w_2.x; B2.y+=(xb)*w_2.y; B2.z+=(xb)*w_2.z; B2.w+=(xb)*w_2.w; \
            B3.x+=(xb)*w_3.x; B3.y+=(xb)*w_3.y; B3.z+=(xb)*w_3.z; B3.w+=(xb)*w_3.w; }
        MSTEP(x0.x, x1.x, 0) MSTEP(x0.y, x1.y, 4) MSTEP(x0.z, x1.z, 8) MSTEP(x0.w, x1.w, 12)
        #undef MSTEP
    }
    float4* ov0 = (float4*)(out + (size_t)row0*CH + c0);
    float4* ov1 = (float4*)(out + (size_t)(row0+256)*CH + c0);
    ov0[0]=A0; ov0[1]=A1; ov0[2]=A2; ov0[3]=A3;
    ov1[0]=B0; ov1[1]=B1; ov1[2]=B2; ov1[3]=B3;
    #define STATQ(q, A, B) { \
        float4 s = make_float4(A.x+B.x, A.y+B.y, A.z+B.z, A.w+B.w); \
        float4 sq = make_float4(A.x*A.x+B.x*B.x, A.y*A.y+B.y*B.y, A.z*A.z+B.z*B.z, A.w*A.w+B.w*B.w); \
        _Pragma("unroll") \
        for (int m=32;m>=1;m>>=1){ \
            s.x+=__shfl_xor(s.x,m); s.y+=__shfl_xor(s.y,m); \
            s.z+=__shfl_xor(s.z,m); s.w+=__shfl_xor(s.w,m); \
            sq.x+=__shfl_xor(sq.x,m); sq.y+=__shfl_xor(sq.y,m); \
            sq.z+=__shfl_xor(sq.z,m); sq.w+=__shfl_xor(sq.w,m); } \
        if ((tid&63)==0){ \
            red[wv][q*4+0]=s.x; red[wv][q*4+1]=s.y; red[wv][q*4+2]=s.z; red[wv][q*4+3]=s.w; \
            red[wv][16+q*4+0]=sq.x; red[wv][16+q*4+1]=sq.y; red[wv][16+q*4+2]=sq.z; red[wv][16+q*4+3]=sq.w; } }
    STATQ(0, A0, B0) STATQ(1, A1, B1) STATQ(2, A2, B2) STATQ(3, A3, B3)
    #undef STATQ
    __syncthreads();
    if (tid < 32) {
        float t = red[0][tid]+red[1][tid]+red[2][tid]+red[3][tid];
        int dstc = (tid<16) ? (c0+tid) : (64 + c0 + (tid-16));
        atomicAdd(&gstat[(blockIdx.x & (NREP-1))*128 + dstc], t);
    }
}

// ---------- final: inline BN3 finalize; relu(bn3(h3) + x_skip) ----------
__global__ __launch_bounds__(256) void k_final(
    const float* __restrict__ h3, const float* __restrict__ x,
    const float* __restrict__ bnrep, const float* __restrict__ gma,
    const float* __restrict__ bta, float* __restrict__ out)
{
    __shared__ float fb[128];
    const int tid = threadIdx.x;
    if (tid < 128){
        float t = 0.f;
        #pragma unroll
        for (int r=0;r<NREP;++r) t += bnrep[r*128+tid];
        fb[tid] = t;
    }
    __syncthreads();
    if (tid < 64){
        float mm = fb[tid]*(1.f/NPTS);
        float vv = fb[64+tid]*(1.f/NPTS) - mm*mm;
        float ss = gma[tid]*rsqrtf(vv+EPS);
        fb[tid] = ss; fb[64+tid] = bta[tid] - mm*ss;
    }
    __syncthreads();
    const int gi = blockIdx.x*256 + tid;
    const int c0 = (gi & 15)*4;
    float sc0=fb[c0],sc1=fb[c0+1],sc2=fb[c0+2],sc3=fb[c0+3];
    float sh0=fb[64+c0],sh1=fb[64+c0+1],sh2=fb[64+c0+2],sh3=fb[64+c0+3];
    float4 h = ((const float4*)h3)[gi];
    float4 xv = ((const float4*)x)[gi];
    float4 o;
    o.x = fmaxf(h.x*sc0+sh0+xv.x, 0.f);
    o.y = fmaxf(h.y*sc1+sh1+xv.y, 0.f);
    o.z = fmaxf(h.z*sc2+sh2+xv.z, 0.f);
    o.w = fmaxf(h.w*sc3+sh3+xv.w, 0.f);
    ((float4*)out)[gi] = o;
}

extern "C" void kernel_launch(void* const* d_in, const int* in_sizes, int n_in,
                              void* d_out, int out_size, void* d_ws, size_t ws_size,
                              hipStream_t stream) {
    (void)in_sizes; (void)n_in; (void)out_size; (void)ws_size;
    const float* pos   = (const float*)d_in[0];
    const float* x     = (const float*)d_in[1];
    const float* W1    = (const float*)d_in[2];
    const float* Wk    = (const float*)d_in[3];
    const float* bk    = (const float*)d_in[4];
    const float* Wq    = (const float*)d_in[5];
    const float* bq    = (const float*)d_in[6];
    const float* Wv    = (const float*)d_in[7];
    const float* bv    = (const float*)d_in[8];
    const float* p1w   = (const float*)d_in[9];
    const float* p1b   = (const float*)d_in[10];
    const float* pg    = (const float*)d_in[11];
    const float* pb    = (const float*)d_in[12];
    const float* p2w   = (const float*)d_in[13];
    const float* p2b   = (const float*)d_in[14];
    const float* w1g   = (const float*)d_in[15];
    const float* w1bb  = (const float*)d_in[16];
    const float* w1w   = (const float*)d_in[17];
    const float* w1bias= (const float*)d_in[18];
    const float* w2g   = (const float*)d_in[19];
    const float* w2bb  = (const float*)d_in[20];
    const float* w2w   = (const float*)d_in[21];
    const float* w2bias= (const float*)d_in[22];
    const float* W3    = (const float*)d_in[23];
    const float* bn1g  = (const float*)d_in[24];
    const float* bn1b  = (const float*)d_in[25];
    const float* bn2g  = (const float*)d_in[26];
    const float* bn2b  = (const float*)d_in[27];
    const float* bn3g  = (const float*)d_in[28];
    const float* bn3b  = (const float*)d_in[29];
    const int*   ei    = (const int*)d_in[30];
    float* ws  = (float*)d_ws;
    float* out = (float*)d_out;
    uint* kb = (uint*)(ws+OFF_K);
    uint* qb = (uint*)(ws+OFF_Q);
    uint* vb = (uint*)(ws+OFF_V);
    uint* a2b = (uint*)(ws+OFF_A2);

    hipMemsetAsync(ws, 0, STATS_FLOATS*sizeof(float), stream);

    // u + p-bn stats (blocks 0..2047) and t1 = x @ W1^T + bn1 stats (blocks 2048..2303)
    k_pg<<<2304, 256, 0, stream>>>(pos, ei, p1w, p1b,
        (float4*)(ws+OFF_U), ws+G_P, x, W1, ws+OFF_T1, ws+G_BN1);
    // k,q,v (bf16), inline BN1 finalize
    k_kqv<<<768, 256, 0, stream>>>(ws+OFF_T1, Wk, bk, Wq, bq, Wv, bv,
        ws+G_BN1, bn1g, bn1b, kb, qb, vb);
    // w_bn1 stats, inline P finalize
    k_edge1<<<8192, 256, 0, stream>>>(ei, (const float4*)(ws+OFF_U),
        (const unsigned short*)kb, (const unsigned short*)qb,
        ws+G_P, pg, pb, p2w, p2b, ws+G_W1);
    // finalize W1 (kept as kernel: edge2 consumes it on the scalar path)
    k_fin1<<<1, 128, 0, stream>>>(ws+G_W1, 1.f/NE, w1g, w1bb, ws+F_W1, 64);
    // a2 + w_bn2 stats, inline P finalize
    k_edge2<<<2048, 256, 0, stream>>>(ei, (const float4*)(ws+OFF_U),
        kb, qb, ws+G_P, pg, pb, p2w, p2b,
        ws+F_W1, w1w, w1bias, a2b, ws+G_W2);
    // softmax + aggregate + bn2 stats, inline P+W2 finalize
    k_attn<<<2048, 256, 0, stream>>>(ei, (const float4*)(ws+OFF_U),
        vb, a2b, ws+G_P, pg, pb, p2w, p2b,
        ws+G_W2, w2g, w2bb, w2w, w2bias, ws+OFF_OUT, ws+G_BN2);
    // h3 = relu(bn2(out)) @ W3^T + bn3 stats, inline BN2 finalize
    k_gemm_bn<<<256, 256, 0, stream>>>(ws+OFF_OUT, W3, ws+OFF_H3,
        ws+G_BN2, bn2g, bn2b, ws+G_BN3);
    // final, inline BN3 finalize
    k_final<<<2048, 256, 0, stream>>>(ws+OFF_H3, x, ws+G_BN3, bn3g, bn3b, out);
}

// Round 11
// 267.332 us; speedup vs baseline: 1.0602x; 1.0602x over previous
//
#include <hip/hip_runtime.h>

#define NPTS 32768
#define CH 64
#define KNN 16
#define NE (NPTS*KNN)
#define EPS 1e-5f
#define NREP 32

// raw stats groups: NREP replicas x 128 floats; sums at [c], sumsq at [64+c]
#define G_P   0
#define G_BN1 (1*NREP*128)
#define G_W1  (2*NREP*128)
#define G_W2  (3*NREP*128)
#define G_BN2 (4*NREP*128)
#define G_BN3 (5*NREP*128)
#define STATS_FLOATS (6*NREP*128)

#define OFF_T1  (STATS_FLOATS + 1024)
#define SZ_NC   (NPTS*CH)
// bf16 buffers (NPTS*32 uints each)
#define OFF_K   (OFF_T1 + SZ_NC)
#define OFF_Q   (OFF_K + NPTS*32)
#define OFF_V   (OFF_Q + NPTS*32)
#define OFF_A2  (OFF_V + NPTS*32)      /* NE*4 uints (8 bf16/edge) */
#define OFF_OUT (OFF_A2 + NE*4)
#define OFF_U   (OFF_OUT + SZ_NC)      /* NE*4 floats; aliased with H3 */
#define OFF_H3  OFF_U

typedef unsigned int uint;

__device__ __forceinline__ float frelu(float x){ return fmaxf(x, 0.f); }
__device__ __forceinline__ float bflo(uint u){ return __uint_as_float(u<<16); }
__device__ __forceinline__ float bfhi(uint u){ return __uint_as_float(u & 0xffff0000u); }
__device__ __forceinline__ uint bfpack(float lo, float hi){
    uint a = __float_as_uint(lo), b = __float_as_uint(hi);
    a = (a + 0x7fffu + ((a>>16)&1u)) >> 16;
    b = ((b + 0x7fffu + ((b>>16)&1u)) >> 16) << 16;
    return a | b;
}

// ---------- merged: blocks 0..2047 = u precompute + p-bn stats; 2048..2303 = gemm1 ----------
__global__ __launch_bounds__(256) void k_pg(
    const float* __restrict__ pos, const int* __restrict__ esrc,
    const float* __restrict__ p1w, const float* __restrict__ p1b,
    float4* __restrict__ u4, float* __restrict__ gstatP,
    const float* __restrict__ in, const float* __restrict__ W,
    float* __restrict__ out, float* __restrict__ gstatB)
{
    __shared__ float Wt[CH*16];
    __shared__ float red[4][32];
    const int tid = threadIdx.x;
    const int wv = tid >> 6;
    if (blockIdx.x < 2048) {
        const float w0=p1w[0],w1=p1w[1],w2=p1w[2],w3=p1w[3],w4=p1w[4],w5=p1w[5],w6=p1w[6],w7=p1w[7],w8=p1w[8];
        const float b0=p1b[0],b1=p1b[1],b2=p1b[2];
        const int e = blockIdx.x*256 + tid;
        const int sj = esrc[e]; const int d = e >> 4;
        float ax = pos[3*sj]-pos[3*d], ay = pos[3*sj+1]-pos[3*d+1], az = pos[3*sj+2]-pos[3*d+2];
        float u0 = w0*ax+w1*ay+w2*az+b0;
        float u1 = w3*ax+w4*ay+w5*az+b1;
        float u2 = w6*ax+w7*ay+w8*az+b2;
        u4[e] = make_float4(u0,u1,u2,0.f);
        float s0=u0,s1=u1,s2=u2,q0=u0*u0,q1=u1*u1,q2=u2*u2;
        #pragma unroll
        for (int m=32;m>=1;m>>=1){
            s0+=__shfl_xor(s0,m); s1+=__shfl_xor(s1,m); s2+=__shfl_xor(s2,m);
            q0+=__shfl_xor(q0,m); q1+=__shfl_xor(q1,m); q2+=__shfl_xor(q2,m);
        }
        if ((tid&63)==0){ red[wv][0]=s0; red[wv][1]=s1; red[wv][2]=s2;
                          red[wv][3]=q0; red[wv][4]=q1; red[wv][5]=q2; }
        __syncthreads();
        float* g = gstatP + (blockIdx.x & (NREP-1))*128;
        if (tid < 3)      atomicAdd(&g[tid],        red[0][tid]+red[1][tid]+red[2][tid]+red[3][tid]);
        else if (tid < 6) atomicAdd(&g[64+(tid-3)], red[0][tid]+red[1][tid]+red[2][tid]+red[3][tid]);
        return;
    }
    const int bid = blockIdx.x - 2048;
    const int rb = bid >> 2;
    const int c0 = (bid & 3)*16;
    #pragma unroll
    for (int ch=0; ch<4; ++ch){
        const int idx = ch*256 + tid;
        Wt[idx] = W[(size_t)(c0 + (idx & 15))*CH + (idx >> 4)];
    }
    __syncthreads();
    const int row0 = rb*512 + tid;
    const float4* iv0 = (const float4*)(in + (size_t)row0*CH);
    const float4* iv1 = (const float4*)(in + (size_t)(row0+256)*CH);
    const float4* Wt4 = (const float4*)Wt;
    float4 A0=make_float4(0,0,0,0),A1=A0,A2=A0,A3=A0;
    float4 B0=A0,B1=A0,B2=A0,B3=A0;
    #pragma unroll 1
    for (int jj=0;jj<16;++jj){
        float4 x0 = iv0[jj], x1 = iv1[jj];
        const float4* wb = &Wt4[jj*16];
        #define MSTEP(xa, xb, base) { \
            float4 w_0=wb[(base)+0], w_1=wb[(base)+1], w_2=wb[(base)+2], w_3=wb[(base)+3]; \
            A0.x+=(xa)*w_0.x; A0.y+=(xa)*w_0.y; A0.z+=(xa)*w_0.z; A0.w+=(xa)*w_0.w; \
            A1.x+=(xa)*w_1.x; A1.y+=(xa)*w_1.y; A1.z+=(xa)*w_1.z; A1.w+=(xa)*w_1.w; \
            A2.x+=(xa)*w_2.x; A2.y+=(xa)*w_2.y; A2.z+=(xa)*w_2.z; A2.w+=(xa)*w_2.w; \
            A3.x+=(xa)*w_3.x; A3.y+=(xa)*w_3.y; A3.z+=(xa)*w_3.z; A3.w+=(xa)*w_3.w; \
            B0.x+=(xb)*w_0.x; B0.y+=(xb)*w_0.y; B0.z+=(xb)*w_0.z; B0.w+=(xb)*w_0.w; \
            B1.x+=(xb)*w_1.x; B1.y+=(xb)*w_1.y; B1.z+=(xb)*w_1.z; B1.w+=(xb)*w_1.w; \
            B2.x+=(xb)*w_2.x; B2.y+=(xb)*w_2.y; B2.z+=(xb)*w_2.z; B2.w+=(xb)*w_2.w; \
            B3.x+=(xb)*w_3.x; B3.y+=(xb)*w_3.y; B3.z+=(xb)*w_3.z; B3.w+=(xb)*w_3.w; }
        MSTEP(x0.x, x1.x, 0) MSTEP(x0.y, x1.y, 4) MSTEP(x0.z, x1.z, 8) MSTEP(x0.w, x1.w, 12)
        #undef MSTEP
    }
    float4* ov0 = (float4*)(out + (size_t)row0*CH + c0);
    float4* ov1 = (float4*)(out + (size_t)(row0+256)*CH + c0);
    ov0[0]=A0; ov0[1]=A1; ov0[2]=A2; ov0[3]=A3;
    ov1[0]=B0; ov1[1]=B1; ov1[2]=B2; ov1[3]=B3;
    #define STATQ(q, A, B) { \
        float4 s = make_float4(A.x+B.x, A.y+B.y, A.z+B.z, A.w+B.w); \
        float4 sq = make_float4(A.x*A.x+B.x*B.x, A.y*A.y+B.y*B.y, A.z*A.z+B.z*B.z, A.w*A.w+B.w*B.w); \
        _Pragma("unroll") \
        for (int m=32;m>=1;m>>=1){ \
            s.x+=__shfl_xor(s.x,m); s.y+=__shfl_xor(s.y,m); \
            s.z+=__shfl_xor(s.z,m); s.w+=__shfl_xor(s.w,m); \
            sq.x+=__shfl_xor(sq.x,m); sq.y+=__shfl_xor(sq.y,m); \
            sq.z+=__shfl_xor(sq.z,m); sq.w+=__shfl_xor(sq.w,m); } \
        if ((tid&63)==0){ \
            red[wv][q*4+0]=s.x; red[wv][q*4+1]=s.y; red[wv][q*4+2]=s.z; red[wv][q*4+3]=s.w; \
            red[wv][16+q*4+0]=sq.x; red[wv][16+q*4+1]=sq.y; red[wv][16+q*4+2]=sq.z; red[wv][16+q*4+3]=sq.w; } }
    STATQ(0, A0, B0) STATQ(1, A1, B1) STATQ(2, A2, B2) STATQ(3, A3, B3)
    #undef STATQ
    __syncthreads();
    if (tid < 32) {
        float t = red[0][tid]+red[1][tid]+red[2][tid]+red[3][tid];
        int dstc = (tid<16) ? (c0+tid) : (64 + c0 + (tid-16));
        atomicAdd(&gstatB[(bid & (NREP-1))*128 + dstc], t);
    }
}

// ---------- k/q/v: grid 768; inline BN1 finalize; bf16-packed outputs ----------
__global__ __launch_bounds__(256) void k_kqv(
    const float* __restrict__ t1,
    const float* __restrict__ Wk, const float* __restrict__ bk,
    const float* __restrict__ Wq, const float* __restrict__ bq,
    const float* __restrict__ Wv, const float* __restrict__ bv,
    const float* __restrict__ bnrep, const float* __restrict__ bn1g,
    const float* __restrict__ bn1b,
    uint* __restrict__ kout, uint* __restrict__ qout, uint* __restrict__ vout)
{
    __shared__ float Wt[CH*16];
    __shared__ float fbnL[128];
    __shared__ float4 bias4[4];
    const int tid = threadIdx.x;
    const int m = blockIdx.x / 256;
    const int rem = blockIdx.x & 255;
    const int rb = rem >> 2;
    const int c0 = (rem & 3)*16;
    const float* W  = (m==0) ? Wk : (m==1 ? Wq : Wv);
    const float* bs = (m==0) ? bk : (m==1 ? bq : bv);
    uint* o         = (m==0) ? kout : (m==1 ? qout : vout);
    #pragma unroll
    for (int ch=0; ch<4; ++ch){
        const int idx = ch*256 + tid;
        Wt[idx] = W[(size_t)(c0 + (idx & 15))*CH + (idx >> 4)];
    }
    if (tid < 128){
        float t = 0.f;
        #pragma unroll
        for (int r=0;r<NREP;++r) t += bnrep[r*128+tid];
        fbnL[tid] = t;
    }
    if (tid < 4)  bias4[tid] = ((const float4*)(bs + c0))[tid];
    __syncthreads();
    if (tid < 64){
        float mm = fbnL[tid]*(1.f/NPTS);
        float vv = fbnL[64+tid]*(1.f/NPTS) - mm*mm;
        float ss = bn1g[tid]*rsqrtf(vv+EPS);
        fbnL[tid] = ss; fbnL[64+tid] = bn1b[tid] - mm*ss;
    }
    __syncthreads();
    const float4* fL = (const float4*)fbnL;

    const int row0 = rb*512 + tid;
    const float4* iv0 = (const float4*)(t1 + (size_t)row0*CH);
    const float4* iv1 = (const float4*)(t1 + (size_t)(row0+256)*CH);
    const float4* Wt4 = (const float4*)Wt;
    float4 A0=bias4[0],A1=bias4[1],A2=bias4[2],A3=bias4[3];
    float4 B0=bias4[0],B1=bias4[1],B2=bias4[2],B3=bias4[3];
    #pragma unroll 1
    for (int jj=0;jj<16;++jj){
        float4 x0 = iv0[jj], x1 = iv1[jj];
        float4 s4 = fL[jj], h4 = fL[16+jj];
        x0.x=frelu(x0.x*s4.x+h4.x); x0.y=frelu(x0.y*s4.y+h4.y);
        x0.z=frelu(x0.z*s4.z+h4.z); x0.w=frelu(x0.w*s4.w+h4.w);
        x1.x=frelu(x1.x*s4.x+h4.x); x1.y=frelu(x1.y*s4.y+h4.y);
        x1.z=frelu(x1.z*s4.z+h4.z); x1.w=frelu(x1.w*s4.w+h4.w);
        const float4* wb = &Wt4[jj*16];
        #define MSTEP(xa, xb, base) { \
            float4 w_0=wb[(base)+0], w_1=wb[(base)+1], w_2=wb[(base)+2], w_3=wb[(base)+3]; \
            A0.x+=(xa)*w_0.x; A0.y+=(xa)*w_0.y; A0.z+=(xa)*w_0.z; A0.w+=(xa)*w_0.w; \
            A1.x+=(xa)*w_1.x; A1.y+=(xa)*w_1.y; A1.z+=(xa)*w_1.z; A1.w+=(xa)*w_1.w; \
            A2.x+=(xa)*w_2.x; A2.y+=(xa)*w_2.y; A2.z+=(xa)*w_2.z; A2.w+=(xa)*w_2.w; \
            A3.x+=(xa)*w_3.x; A3.y+=(xa)*w_3.y; A3.z+=(xa)*w_3.z; A3.w+=(xa)*w_3.w; \
            B0.x+=(xb)*w_0.x; B0.y+=(xb)*w_0.y; B0.z+=(xb)*w_0.z; B0.w+=(xb)*w_0.w; \
            B1.x+=(xb)*w_1.x; B1.y+=(xb)*w_1.y; B1.z+=(xb)*w_1.z; B1.w+=(xb)*w_1.w; \
            B2.x+=(xb)*w_2.x; B2.y+=(xb)*w_2.y; B2.z+=(xb)*w_2.z; B2.w+=(xb)*w_2.w; \
            B3.x+=(xb)*w_3.x; B3.y+=(xb)*w_3.y; B3.z+=(xb)*w_3.z; B3.w+=(xb)*w_3.w; }
        MSTEP(x0.x, x1.x, 0) MSTEP(x0.y, x1.y, 4) MSTEP(x0.z, x1.z, 8) MSTEP(x0.w, x1.w, 12)
        #undef MSTEP
    }
    uint4 pa, pb_;
    pa.x = bfpack(A0.x,A0.y); pa.y = bfpack(A0.z,A0.w);
    pa.z = bfpack(A1.x,A1.y); pa.w = bfpack(A1.z,A1.w);
    pb_.x = bfpack(A2.x,A2.y); pb_.y = bfpack(A2.z,A2.w);
    pb_.z = bfpack(A3.x,A3.y); pb_.w = bfpack(A3.z,A3.w);
    uint4* o0 = (uint4*)(o + (size_t)row0*32 + (c0>>1));
    o0[0]=pa; o0[1]=pb_;
    pa.x = bfpack(B0.x,B0.y); pa.y = bfpack(B0.z,B0.w);
    pa.z = bfpack(B1.x,B1.y); pa.w = bfpack(B1.z,B1.w);
    pb_.x = bfpack(B2.x,B2.y); pb_.y = bfpack(B2.z,B2.w);
    pb_.z = bfpack(B3.x,B3.y); pb_.w = bfpack(B3.z,B3.w);
    uint4* o1 = (uint4*)(o + (size_t)(row0+256)*32 + (c0>>1));
    o1[0]=pa; o1[1]=pb_;
}

// ---------- w_bn1 stats; inline P finalize; 4 ch/lane x 4 edges/wave, uint2 loads ----------
// grid 4096 x 256: wave gw handles edges [gw*32, gw*32+32)
__global__ __launch_bounds__(256) void k_edge1(
    const int* __restrict__ esrc, const float4* __restrict__ u4,
    const uint* __restrict__ kbuf, const uint* __restrict__ qbuf,
    const float* __restrict__ gP, const float* __restrict__ pg,
    const float* __restrict__ pb,
    const float* __restrict__ p2w, const float* __restrict__ p2b,
    float* __restrict__ gstat)
{
    __shared__ float red[4][128];
    __shared__ float pf[6];
    const int tid = threadIdx.x;
    const int wv = tid >> 6;
    const int lane = tid & 63;
    const int sub = lane >> 4;      // which of 4 concurrent edges
    const int cl  = lane & 15;      // channel quad: channels 4cl..4cl+3
    if (tid < 6){
        int idx = (tid<3) ? tid : 64+(tid-3);
        float t = 0.f;
        #pragma unroll
        for (int r=0;r<NREP;++r) t += gP[r*128+idx];
        pf[tid] = t;
    }
    __syncthreads();
    const float m0=pf[0]*(1.f/NE), m1=pf[1]*(1.f/NE), m2=pf[2]*(1.f/NE);
    const float scp0=pg[0]*rsqrtf(pf[3]*(1.f/NE)-m0*m0+EPS);
    const float scp1=pg[1]*rsqrtf(pf[4]*(1.f/NE)-m1*m1+EPS);
    const float scp2=pg[2]*rsqrtf(pf[5]*(1.f/NE)-m2*m2+EPS);
    const float shp0=pb[0]-m0*scp0, shp1=pb[1]-m1*scp1, shp2=pb[2]-m2*scp2;
    const int c0 = cl*4;
    float pw[12], pbv4[4];
    #pragma unroll
    for (int k2=0;k2<12;++k2) pw[k2] = p2w[c0*3+k2];
    #pragma unroll
    for (int k2=0;k2<4;++k2)  pbv4[k2] = p2b[c0+k2];

    const int gw = blockIdx.x*4 + wv;      // 16384 waves
    const int e0 = gw*32;
    float s0a=0,s1a=0,s2a=0,s3a=0, q0a=0,q1a=0,q2a=0,q3a=0;
    #pragma unroll 2
    for (int it=0; it<8; ++it){
        const int e = e0 + it*4 + sub;
        const int sj = esrc[e]; const int d = e >> 4;
        float4 uu = u4[e];
        float r0 = frelu(uu.x*scp0+shp0);
        float r1 = frelu(uu.y*scp1+shp1);
        float r2 = frelu(uu.z*scp2+shp2);
        uint2 ku = ((const uint2*)kbuf)[(size_t)sj*16 + cl];
        uint2 qu = ((const uint2*)qbuf)[(size_t)d*16 + cl];
        float a0 = bflo(ku.x)-bflo(qu.x) + (r0*pw[0]+r1*pw[1]+r2*pw[2]+pbv4[0]);
        float a1 = bfhi(ku.x)-bfhi(qu.x) + (r0*pw[3]+r1*pw[4]+r2*pw[5]+pbv4[1]);
        float a2 = bflo(ku.y)-bflo(qu.y) + (r0*pw[6]+r1*pw[7]+r2*pw[8]+pbv4[2]);
        float a3 = bfhi(ku.y)-bfhi(qu.y) + (r0*pw[9]+r1*pw[10]+r2*pw[11]+pbv4[3]);
        s0a+=a0; s1a+=a1; s2a+=a2; s3a+=a3;
        q0a+=a0*a0; q1a+=a1*a1; q2a+=a2*a2; q3a+=a3*a3;
    }
    #pragma unroll
    for (int msk=16; msk<=32; msk<<=1){
        s0a+=__shfl_xor(s0a,msk); s1a+=__shfl_xor(s1a,msk);
        s2a+=__shfl_xor(s2a,msk); s3a+=__shfl_xor(s3a,msk);
        q0a+=__shfl_xor(q0a,msk); q1a+=__shfl_xor(q1a,msk);
        q2a+=__shfl_xor(q2a,msk); q3a+=__shfl_xor(q3a,msk);
    }
    if (lane < 16){
        red[wv][c0+0]=s0a; red[wv][c0+1]=s1a; red[wv][c0+2]=s2a; red[wv][c0+3]=s3a;
        red[wv][64+c0+0]=q0a; red[wv][64+c0+1]=q1a; red[wv][64+c0+2]=q2a; red[wv][64+c0+3]=q3a;
    }
    __syncthreads();
    if (tid < 128) {
        float t = red[0][tid]+red[1][tid]+red[2][tid]+red[3][tid];
        atomicAdd(&gstat[(blockIdx.x & (NREP-1))*128 + tid], t);
    }
}

// ---------- a2 = relu(bn_w1(apre))@w1^T+b1 ; inline P + W1 finalize; thread = edge; bf16 ----------
__global__ __launch_bounds__(256) void k_edge2(
    const int* __restrict__ esrc, const float4* __restrict__ u4,
    const uint* __restrict__ kbuf, const uint* __restrict__ qbuf,
    const float* __restrict__ gP, const float* __restrict__ pg,
    const float* __restrict__ pb,
    const float* __restrict__ p2w, const float* __restrict__ p2b,
    const float* __restrict__ gW1, const float* __restrict__ w1g,
    const float* __restrict__ w1bb,
    const float* __restrict__ w1w, const float* __restrict__ w1bias,
    uint* __restrict__ a2out, float* __restrict__ gstat)
{
    __shared__ float red[4][16];
    __shared__ float pf[6];
    __shared__ float fW1L[128];
    const int tid = threadIdx.x;
    if (tid < 6){
        int idx = (tid<3) ? tid : 64+(tid-3);
        float t = 0.f;
        #pragma unroll
        for (int r=0;r<NREP;++r) t += gP[r*128+idx];
        pf[tid] = t;
    }
    if (tid >= 64 && tid < 192){
        const int j = tid - 64;
        float t = 0.f;
        #pragma unroll
        for (int r=0;r<NREP;++r) t += gW1[r*128+j];
        fW1L[j] = t;
    }
    __syncthreads();
    if (tid < 64){
        float mm = fW1L[tid]*(1.f/NE);
        float vv = fW1L[64+tid]*(1.f/NE) - mm*mm;
        float ss = w1g[tid]*rsqrtf(vv+EPS);
        fW1L[tid] = ss; fW1L[64+tid] = w1bb[tid] - mm*ss;
    }
    __syncthreads();
    const float m0=pf[0]*(1.f/NE), m1=pf[1]*(1.f/NE), m2=pf[2]*(1.f/NE);
    const float scp0=pg[0]*rsqrtf(pf[3]*(1.f/NE)-m0*m0+EPS);
    const float scp1=pg[1]*rsqrtf(pf[4]*(1.f/NE)-m1*m1+EPS);
    const float scp2=pg[2]*rsqrtf(pf[5]*(1.f/NE)-m2*m2+EPS);
    const float shp0=pb[0]-m0*scp0, shp1=pb[1]-m1*scp1, shp2=pb[2]-m2*scp2;

    const int e = blockIdx.x*256 + tid;    // 2048 blocks, one edge/thread
    const int sj = esrc[e]; const int d = e >> 4;
    float4 uu = u4[e];
    const float r0 = frelu(uu.x*scp0+shp0);
    const float r1 = frelu(uu.y*scp1+shp1);
    const float r2 = frelu(uu.z*scp2+shp2);
    const uint4* kv = (const uint4*)(kbuf + (size_t)sj*32);
    const uint4* qv = (const uint4*)(qbuf + (size_t)d*32);
    float a2a[8];
    #pragma unroll
    for (int j=0;j<8;++j) a2a[j] = w1bias[j];
    #pragma unroll
    for (int cc=0; cc<8; ++cc) {
        uint4 ku = kv[cc], qu = qv[cc];
        const int c0 = cc*8;
        float kq[8];
        kq[0]=bflo(ku.x)-bflo(qu.x); kq[1]=bfhi(ku.x)-bfhi(qu.x);
        kq[2]=bflo(ku.y)-bflo(qu.y); kq[3]=bfhi(ku.y)-bfhi(qu.y);
        kq[4]=bflo(ku.z)-bflo(qu.z); kq[5]=bfhi(ku.z)-bfhi(qu.z);
        kq[6]=bflo(ku.w)-bflo(qu.w); kq[7]=bfhi(ku.w)-bfhi(qu.w);
        #pragma unroll
        for (int p=0;p<8;++p){
            const int c = c0+p;
            float b = frelu((kq[p] + r0*p2w[c*3]+r1*p2w[c*3+1]+r2*p2w[c*3+2]+p2b[c])*fW1L[c]+fW1L[64+c]);
            #pragma unroll
            for (int j=0;j<8;++j) a2a[j] += b*w1w[j*64+c];
        }
    }
    uint4 au;
    au.x = bfpack(a2a[0],a2a[1]); au.y = bfpack(a2a[2],a2a[3]);
    au.z = bfpack(a2a[4],a2a[5]); au.w = bfpack(a2a[6],a2a[7]);
    ((uint4*)a2out)[e] = au;
    float q8[8];
    #pragma unroll
    for (int j=0;j<8;++j) q8[j]=a2a[j]*a2a[j];
    #pragma unroll
    for (int m=32;m>=1;m>>=1){
        #pragma unroll
        for (int j=0;j<8;++j){ a2a[j]+=__shfl_xor(a2a[j],m); q8[j]+=__shfl_xor(q8[j],m); }
    }
    const int wv = tid>>6;
    if ((tid&63)==0){
        #pragma unroll
        for (int j=0;j<8;++j){ red[wv][j]=a2a[j]; red[wv][8+j]=q8[j]; }
    }
    __syncthreads();
    if (tid < 16) {
        float t = red[0][tid]+red[1][tid]+red[2][tid]+red[3][tid];
        int dstc = (tid<8) ? tid : (64 + tid - 8);
        atomicAdd(&gstat[(blockIdx.x & (NREP-1))*128 + dstc], t);
    }
}

// ---------- inline P+W2 finalize; bn_w2 + w2 + softmax (A); aggregation (B) + bn2 stats ----------
__global__ __launch_bounds__(256) void k_attn(
    const int* __restrict__ esrc, const float4* __restrict__ u4,
    const uint* __restrict__ vbuf, const uint* __restrict__ a2buf,
    const float* __restrict__ gP, const float* __restrict__ pg,
    const float* __restrict__ pb,
    const float* __restrict__ p2w, const float* __restrict__ p2b,
    const float* __restrict__ gW2, const float* __restrict__ w2g,
    const float* __restrict__ w2bb,
    const float* __restrict__ w2w, const float* __restrict__ w2bias,
    float* __restrict__ outbuf, float* __restrict__ gstat)
{
    __shared__ float red[4][128];
    __shared__ float att[256][8];
    __shared__ float rrL[256][4];
    __shared__ int   sjL[256];
    __shared__ float cf[22];     // [0..5] P raw; [6..13] W2 sum; [14..21] W2 sumsq
    const int tid = threadIdx.x;
    if (tid < 6){
        int idx = (tid<3) ? tid : 64+(tid-3);
        float t = 0.f;
        #pragma unroll
        for (int r=0;r<NREP;++r) t += gP[r*128+idx];
        cf[tid] = t;
    } else if (tid < 22){
        int j = tid - 6;
        int idx = (j<8) ? j : 64+(j-8);
        float t = 0.f;
        #pragma unroll
        for (int r=0;r<NREP;++r) t += gW2[r*128+idx];
        cf[tid] = t;
    }
    __syncthreads();
    const float m0=cf[0]*(1.f/NE), m1=cf[1]*(1.f/NE), m2=cf[2]*(1.f/NE);
    const float scp0=pg[0]*rsqrtf(cf[3]*(1.f/NE)-m0*m0+EPS);
    const float scp1=pg[1]*rsqrtf(cf[4]*(1.f/NE)-m1*m1+EPS);
    const float scp2=pg[2]*rsqrtf(cf[5]*(1.f/NE)-m2*m2+EPS);
    const float shp0=pb[0]-m0*scp0, shp1=pb[1]-m1*scp1, shp2=pb[2]-m2*scp2;

    const int t = tid & 15;
    const int i = blockIdx.x*16 + (tid>>4);
    const int e = i*KNN + t;
    const int sj = esrc[e];
    sjL[tid] = sj;
    {
        float4 uu = u4[e];
        rrL[tid][0] = frelu(uu.x*scp0+shp0);
        rrL[tid][1] = frelu(uu.y*scp1+shp1);
        rrL[tid][2] = frelu(uu.z*scp2+shp2);
    }
    // ---- phase A ----
    {
        float sc2[8], sh2[8];
        #pragma unroll
        for (int j2=0;j2<8;++j2){
            float mm = cf[6+j2]*(1.f/NE);
            float vv = cf[14+j2]*(1.f/NE) - mm*mm;
            float ss = w2g[j2]*rsqrtf(vv+EPS);
            sc2[j2]=ss; sh2[j2]=w2bb[j2]-mm*ss;
        }
        uint4 au = ((const uint4*)a2buf)[e];
        float bb[8];
        bb[0]=frelu(bflo(au.x)*sc2[0]+sh2[0]); bb[1]=frelu(bfhi(au.x)*sc2[1]+sh2[1]);
        bb[2]=frelu(bflo(au.y)*sc2[2]+sh2[2]); bb[3]=frelu(bfhi(au.y)*sc2[3]+sh2[3]);
        bb[4]=frelu(bflo(au.z)*sc2[4]+sh2[4]); bb[5]=frelu(bfhi(au.z)*sc2[5]+sh2[5]);
        bb[6]=frelu(bflo(au.w)*sc2[6]+sh2[6]); bb[7]=frelu(bfhi(au.w)*sc2[7]+sh2[7]);
        float at[8];
        #pragma unroll
        for (int s=0;s<8;++s){
            float a3 = w2bias[s];
            #pragma unroll
            for (int u=0;u<8;++u) a3 += bb[u]*w2w[s*8+u];
            float m = a3;
            #pragma unroll
            for (int msk=8;msk>=1;msk>>=1) m = fmaxf(m, __shfl_xor(m,msk));
            float p = __expf(a3-m);
            float ssm = p;
            #pragma unroll
            for (int msk=8;msk>=1;msk>>=1) ssm += __shfl_xor(ssm,msk);
            at[s] = p/ssm;
        }
        ((float4*)att[tid])[0] = make_float4(at[0],at[1],at[2],at[3]);
        ((float4*)att[tid])[1] = make_float4(at[4],at[5],at[6],at[7]);
    }
    __syncthreads();
    // ---- phase B: thread owns channels 4t..4t+3 of point i ----
    const int base = (tid>>4)*16;
    const int c0 = 4*t;
    const int ho = (t&1);
    float pw[12], pbv[4];
    #pragma unroll
    for (int k2=0;k2<12;++k2) pw[k2] = p2w[c0*3+k2];
    #pragma unroll
    for (int k2=0;k2<4;++k2)  pbv[k2] = p2b[c0+k2];
    float4 res = make_float4(0,0,0,0);
    #pragma unroll 4
    for (int n=0; n<16; ++n){
        const int sjn = sjL[base+n];
        uint2 vv = ((const uint2*)(vbuf + (size_t)sjn*32))[t];
        const float v0=bflo(vv.x), v1=bfhi(vv.x), v2=bflo(vv.y), v3=bfhi(vv.y);
        const float rr0 = rrL[base+n][0], rr1 = rrL[base+n][1], rr2 = rrL[base+n][2];
        float4 a4 = ((const float4*)att[base+n])[ho];
        res.x += a4.x*(v0 + rr0*pw[0]+rr1*pw[1]+rr2*pw[2]+pbv[0]);
        res.y += a4.y*(v1 + rr0*pw[3]+rr1*pw[4]+rr2*pw[5]+pbv[1]);
        res.z += a4.z*(v2 + rr0*pw[6]+rr1*pw[7]+rr2*pw[8]+pbv[2]);
        res.w += a4.w*(v3 + rr0*pw[9]+rr1*pw[10]+rr2*pw[11]+pbv[3]);
    }
    ((float4*)outbuf)[(size_t)i*16 + t] = res;

    // fused bn2 stats
    float4 sq = make_float4(res.x*res.x, res.y*res.y, res.z*res.z, res.w*res.w);
    #pragma unroll
    for (int msk=32;msk>=16;msk>>=1){
        res.x+=__shfl_xor(res.x,msk); res.y+=__shfl_xor(res.y,msk);
        res.z+=__shfl_xor(res.z,msk); res.w+=__shfl_xor(res.w,msk);
        sq.x+=__shfl_xor(sq.x,msk);  sq.y+=__shfl_xor(sq.y,msk);
        sq.z+=__shfl_xor(sq.z,msk);  sq.w+=__shfl_xor(sq.w,msk);
    }
    const int wv = tid>>6;
    if ((tid&63) < 16){
        red[wv][t*4+0]=res.x; red[wv][t*4+1]=res.y; red[wv][t*4+2]=res.z; red[wv][t*4+3]=res.w;
        red[wv][64+t*4+0]=sq.x; red[wv][64+t*4+1]=sq.y; red[wv][64+t*4+2]=sq.z; red[wv][64+t*4+3]=sq.w;
    }
    __syncthreads();
    if (tid < 128) {
        float tt = red[0][tid]+red[1][tid]+red[2][tid]+red[3][tid];
        atomicAdd(&gstat[(blockIdx.x & (NREP-1))*128 + tid], tt);
    }
}

// ---------- gemm2: inline BN2 finalize, bn+relu input, W3 matvec, bn3 stats ----------
__global__ __launch_bounds__(256) void k_gemm_bn(
    const float* __restrict__ in, const float* __restrict__ W,
    float* __restrict__ out,
    const float* __restrict__ bnrep, const float* __restrict__ gma,
    const float* __restrict__ bta,
    float* __restrict__ gstat)
{
    __shared__ float Wt[CH*16];
    __shared__ float fbnL[128];
    __shared__ float red[4][32];
    const int tid = threadIdx.x;
    const int wv = tid >> 6;
    const int rb = blockIdx.x >> 2;
    const int c0 = (blockIdx.x & 3)*16;
    #pragma unroll
    for (int ch=0; ch<4; ++ch){
        const int idx = ch*256 + tid;
        Wt[idx] = W[(size_t)(c0 + (idx & 15))*CH + (idx >> 4)];
    }
    if (tid < 128){
        float t = 0.f;
        #pragma unroll
        for (int r=0;r<NREP;++r) t += bnrep[r*128+tid];
        fbnL[tid] = t;
    }
    __syncthreads();
    if (tid < 64){
        float mm = fbnL[tid]*(1.f/NPTS);
        float vv = fbnL[64+tid]*(1.f/NPTS) - mm*mm;
        float ss = gma[tid]*rsqrtf(vv+EPS);
        fbnL[tid] = ss; fbnL[64+tid] = bta[tid] - mm*ss;
    }
    __syncthreads();
    const float4* fL = (const float4*)fbnL;

    const int row0 = rb*512 + tid;
    const float4* iv0 = (const float4*)(in + (size_t)row0*CH);
    const float4* iv1 = (const float4*)(in + (size_t)(row0+256)*CH);
    const float4* Wt4 = (const float4*)Wt;
    float4 A0=make_float4(0,0,0,0),A1=A0,A2=A0,A3=A0;
    float4 B0=A0,B1=A0,B2=A0,B3=A0;
    #pragma unroll 1
    for (int jj=0;jj<16;++jj){
        float4 x0 = iv0[jj], x1 = iv1[jj];
        float4 s4 = fL[jj], h4 = fL[16+jj];
        x0.x=frelu(x0.x*s4.x+h4.x); x0.y=frelu(x0.y*s4.y+h4.y);
        x0.z=frelu(x0.z*s4.z+h4.z); x0.w=frelu(x0.w*s4.w+h4.w);
        x1.x=frelu(x1.x*s4.x+h4.x); x1.y=frelu(x1.y*s4.y+h4.y);
        x1.z=frelu(x1.z*s4.z+h4.z); x1.w=frelu(x1.w*s4.w+h4.w);
        const float4* wb = &Wt4[jj*16];
        #define MSTEP(xa, xb, base) { \
            float4 w_0=wb[(base)+0], w_1=wb[(base)+1], w_2=wb[(base)+2], w_3=wb[(base)+3]; \
            A0.x+=(xa)*w_0.x; A0.y+=(xa)*w_0.y; A0.z+=(xa)*w_0.z; A0.w+=(xa)*w_0.w; \
            A1.x+=(xa)*w_1.x; A1.y+=(xa)*w_1.y; A1.z+=(xa)*w_1.z; A1.w+=(xa)*w_1.w; \
            A2.x+=(xa)*w_2.x; A2.y+=(xa)*w_2.y; A2.z+=(xa)*w_2.z; A2.w+=(xa)*w_2.w; \
            A3.x+=(xa)*w_3.x; A3.y+=(xa)*w_3.y; A3.z+=(xa)*w_3.z; A3.w+=(xa)*w_3.w; \
            B0.x+=(xb)*w_0.x; B0.y+=(xb)*w_0.y; B0.z+=(xb)*w_0.z; B0.w+=(xb)*w_0.w; \
            B1.x+=(xb)*w_1.x; B1.y+=(xb)*w_1.y; B1.z+=(xb)*w_1.z; B1.w+=(xb)*w_1.w; \
            B2.x+=(xb)*w_2.x; B2.y+=(xb)*w_2.y; B2.z+=(xb)*w_2.z; B2.w+=(xb)*w_2.w; \
            B3.x+=(xb)*w_3.x; B3.y+=(xb)*w_3.y; B3.z+=(xb)*w_3.z; B3.w+=(xb)*w_3.w; }
        MSTEP(x0.x, x1.x, 0) MSTEP(x0.y, x1.y, 4) MSTEP(x0.z, x1.z, 8) MSTEP(x0.w, x1.w, 12)
        #undef MSTEP
    }
    float4* ov0 = (float4*)(out + (size_t)row0*CH + c0);
    float4* ov1 = (float4*)(out + (size_t)(row0+256)*CH + c0);
    ov0[0]=A0; ov0[1]=A1; ov0[2]=A2; ov0[3]=A3;
    ov1[0]=B0; ov1[1]=B1; ov1[2]=B2; ov1[3]=B3;
    #define STATQ(q, A, B) { \
        float4 s = make_float4(A.x+B.x, A.y+B.y, A.z+B.z, A.w+B.w); \
        float4 sq = make_float4(A.x*A.x+B.x*B.x, A.y*A.y+B.y*B.y, A.z*A.z+B.z*B.z, A.w*A.w+B.w*B.w); \
        _Pragma("unroll") \
        for (int m=32;m>=1;m>>=1){ \
            s.x+=__shfl_xor(s.x,m); s.y+=__shfl_xor(s.y,m); \
            s.z+=__shfl_xor(s.z,m); s.w+=__shfl_xor(s.w,m); \
            sq.x+=__shfl_xor(sq.x,m); sq.y+=__shfl_xor(sq.y,m); \
            sq.z+=__shfl_xor(sq.z,m); sq.w+=__shfl_xor(sq.w,m); } \
        if ((tid&63)==0){ \
            red[wv][q*4+0]=s.x; red[wv][q*4+1]=s.y; red[wv][q*4+2]=s.z; red[wv][q*4+3]=s.w; \
            red[wv][16+q*4+0]=sq.x; red[wv][16+q*4+1]=sq.y; red[wv][16+q*4+2]=sq.z; red[wv][16+q*4+3]=sq.w; } }
    STATQ(0, A0, B0) STATQ(1, A1, B1) STATQ(2, A2, B2) STATQ(3, A3, B3)
    #undef STATQ
    __syncthreads();
    if (tid < 32) {
        float t = red[0][tid]+red[1][tid]+red[2][tid]+red[3][tid];
        int dstc = (tid<16) ? (c0+tid) : (64 + c0 + (tid-16));
        atomicAdd(&gstat[(blockIdx.x & (NREP-1))*128 + dstc], t);
    }
}

// ---------- final: inline BN3 finalize; relu(bn3(h3) + x_skip) ----------
__global__ __launch_bounds__(256) void k_final(
    const float* __restrict__ h3, const float* __restrict__ x,
    const float* __restrict__ bnrep, const float* __restrict__ gma,
    const float* __restrict__ bta, float* __restrict__ out)
{
    __shared__ float fb[128];
    const int tid = threadIdx.x;
    if (tid < 128){
        float t = 0.f;
        #pragma unroll
        for (int r=0;r<NREP;++r) t += bnrep[r*128+tid];
        fb[tid] = t;
    }
    __syncthreads();
    if (tid < 64){
        float mm = fb[tid]*(1.f/NPTS);
        float vv = fb[64+tid]*(1.f/NPTS) - mm*mm;
        float ss = gma[tid]*rsqrtf(vv+EPS);
        fb[tid] = ss; fb[64+tid] = bta[tid] - mm*ss;
    }
    __syncthreads();
    const int gi = blockIdx.x*256 + tid;
    const int c0 = (gi & 15)*4;
    float sc0=fb[c0],sc1=fb[c0+1],sc2=fb[c0+2],sc3=fb[c0+3];
    float sh0=fb[64+c0],sh1=fb[64+c0+1],sh2=fb[64+c0+2],sh3=fb[64+c0+3];
    float4 h = ((const float4*)h3)[gi];
    float4 xv = ((const float4*)x)[gi];
    float4 o;
    o.x = fmaxf(h.x*sc0+sh0+xv.x, 0.f);
    o.y = fmaxf(h.y*sc1+sh1+xv.y, 0.f);
    o.z = fmaxf(h.z*sc2+sh2+xv.z, 0.f);
    o.w = fmaxf(h.w*sc3+sh3+xv.w, 0.f);
    ((float4*)out)[gi] = o;
}

extern "C" void kernel_launch(void* const* d_in, const int* in_sizes, int n_in,
                              void* d_out, int out_size, void* d_ws, size_t ws_size,
                              hipStream_t stream) {
    (void)in_sizes; (void)n_in; (void)out_size; (void)ws_size;
    const float* pos   = (const float*)d_in[0];
    const float* x     = (const float*)d_in[1];
    const float* W1    = (const float*)d_in[2];
    const float* Wk    = (const float*)d_in[3];
    const float* bk    = (const float*)d_in[4];
    const float* Wq    = (const float*)d_in[5];
    const float* bq    = (const float*)d_in[6];
    const float* Wv    = (const float*)d_in[7];
    const float* bv    = (const float*)d_in[8];
    const float* p1w   = (const float*)d_in[9];
    const float* p1b   = (const float*)d_in[10];
    const float* pg    = (const float*)d_in[11];
    const float* pb    = (const float*)d_in[12];
    const float* p2w   = (const float*)d_in[13];
    const float* p2b   = (const float*)d_in[14];
    const float* w1g   = (const float*)d_in[15];
    const float* w1bb  = (const float*)d_in[16];
    const float* w1w   = (const float*)d_in[17];
    const float* w1bias= (const float*)d_in[18];
    const float* w2g   = (const float*)d_in[19];
    const float* w2bb  = (const float*)d_in[20];
    const float* w2w   = (const float*)d_in[21];
    const float* w2bias= (const float*)d_in[22];
    const float* W3    = (const float*)d_in[23];
    const float* bn1g  = (const float*)d_in[24];
    const float* bn1b  = (const float*)d_in[25];
    const float* bn2g  = (const float*)d_in[26];
    const float* bn2b  = (const float*)d_in[27];
    const float* bn3g  = (const float*)d_in[28];
    const float* bn3b  = (const float*)d_in[29];
    const int*   ei    = (const int*)d_in[30];
    float* ws  = (float*)d_ws;
    float* out = (float*)d_out;
    uint* kb = (uint*)(ws+OFF_K);
    uint* qb = (uint*)(ws+OFF_Q);
    uint* vb = (uint*)(ws+OFF_V);
    uint* a2b = (uint*)(ws+OFF_A2);

    hipMemsetAsync(ws, 0, STATS_FLOATS*sizeof(float), stream);

    // u + p-bn stats (blocks 0..2047) and t1 = x @ W1^T + bn1 stats (blocks 2048..2303)
    k_pg<<<2304, 256, 0, stream>>>(pos, ei, p1w, p1b,
        (float4*)(ws+OFF_U), ws+G_P, x, W1, ws+OFF_T1, ws+G_BN1);
    // k,q,v (bf16), inline BN1 finalize
    k_kqv<<<768, 256, 0, stream>>>(ws+OFF_T1, Wk, bk, Wq, bq, Wv, bv,
        ws+G_BN1, bn1g, bn1b, kb, qb, vb);
    // w_bn1 stats, inline P finalize, vectorized gather
    k_edge1<<<4096, 256, 0, stream>>>(ei, (const float4*)(ws+OFF_U),
        kb, qb, ws+G_P, pg, pb, p2w, p2b, ws+G_W1);
    // a2 + w_bn2 stats, inline P + W1 finalize
    k_edge2<<<2048, 256, 0, stream>>>(ei, (const float4*)(ws+OFF_U),
        kb, qb, ws+G_P, pg, pb, p2w, p2b,
        ws+G_W1, w1g, w1bb, w1w, w1bias, a2b, ws+G_W2);
    // softmax + aggregate + bn2 stats, inline P+W2 finalize
    k_attn<<<2048, 256, 0, stream>>>(ei, (const float4*)(ws+OFF_U),
        vb, a2b, ws+G_P, pg, pb, p2w, p2b,
        ws+G_W2, w2g, w2bb, w2w, w2bias, ws+OFF_OUT, ws+G_BN2);
    // h3 = relu(bn2(out)) @ W3^T + bn3 stats, inline BN2 finalize
    k_gemm_bn<<<256, 256, 0, stream>>>(ws+OFF_OUT, W3, ws+OFF_H3,
        ws+G_BN2, bn2g, bn2b, ws+G_BN3);
    // final, inline BN3 finalize
    k_final<<<2048, 256, 0, stream>>>(ws+OFF_H3, x, ws+G_BN3, bn3g, bn3b, out);
}